// Round 4
// baseline (329.075 us; speedup 1.0000x reference)
//
#include <hip/hip_runtime.h>

// LSTM cell fused, round 7: K-loop restructured from 4-phase/8-barrier per
// K-tile to TRIPLE-BUFFERED BK=32 steps with ONE barrier per step
// (AITER pattern: 32 MFMA per barrier, counted vmcnt(4), loads never
// drained to 0 mid-loop). Stores at step t go to buf (t+2)%3 which no wave
// reads at step t (skew <1 step via the step-end barrier) -> no mid-step
// barriers needed. LDS 3x32KB=96KB; same proven 0-conflict geometry
// (64B rows, chunk^=(row>>1)&3); fragment/output mapping and epilogue
// identical to round 6. prep unchanged (decomposition experiment).

#define BDIM 8192
#define KDIM 2048
#define NDIM 1024
#define NCAT 4096
#define NK   64      // KDIM / 32

typedef __bf16 bf16x8 __attribute__((ext_vector_type(8)));
typedef float  f32x4  __attribute__((ext_vector_type(4)));

__device__ __forceinline__ void async_cp16(const void* g, void* l) {
    __builtin_amdgcn_global_load_lds((__attribute__((address_space(1))) void*)g,
                                     (__attribute__((address_space(3))) void*)l,
                                     16, 0, 0);
}

__device__ __forceinline__ float sigm(float x) { return 1.f / (1.f + __expf(-x)); }
__device__ __forceinline__ float tanh_fast(float x) { return 1.f - 2.f / (1.f + __expf(2.f * x)); }

#define BARM asm volatile("s_barrier" ::: "memory")

// ---------------- prep: A pack + weight transpose (unchanged) ----------------
__global__ __launch_bounds__(256)
void prep_kernel(const float* __restrict__ Z, const float* __restrict__ H,
                 const float* __restrict__ Wi, const float* __restrict__ Wf,
                 const float* __restrict__ Wo, const float* __restrict__ Wg,
                 __bf16* __restrict__ A, __bf16* __restrict__ Wt) {
    __shared__ float t[64][65];
    const int bid = blockIdx.x;
    const int tid = threadIdx.x;

    if (bid < 8192) {
        const bool isZ = (bid < 4096);
        const int idx  = (isZ ? bid : bid - 4096) * 256 + tid;
        const int row  = idx >> 7;
        const int q8   = idx & 127;
        const float* src = isZ ? Z : H;
        const float4* p = (const float4*)src + ((size_t)row << 8) + q8 * 2;
        float4 v0 = p[0], v1 = p[1];
        bf16x8 o = { (__bf16)v0.x, (__bf16)v0.y, (__bf16)v0.z, (__bf16)v0.w,
                     (__bf16)v1.x, (__bf16)v1.y, (__bf16)v1.z, (__bf16)v1.w };
        const int col8 = isZ ? q8 : (q8 + 128);
        ((bf16x8*)A)[(size_t)row * 256 + col8] = o;
    } else {
        const int id  = bid - 8192;
        const int g   = id >> 9;
        const int rem = id & 511;
        const int k0  = (rem & 31) * 64;
        const int n0  = (rem >> 5) * 64;
        const float* W = (g == 0) ? Wi : (g == 1) ? Wf : (g == 2) ? Wo : Wg;

        const int c4 = tid & 15, r0 = tid >> 4;
        #pragma unroll
        for (int it = 0; it < 4; ++it) {
            const int r = r0 + it * 16;
            float4 v = ((const float4*)W)[(size_t)(k0 + r) * 256 + (n0 >> 2) + c4];
            t[r][c4 * 4 + 0] = v.x;
            t[r][c4 * 4 + 1] = v.y;
            t[r][c4 * 4 + 2] = v.z;
            t[r][c4 * 4 + 3] = v.w;
        }
        __syncthreads();

        const int kc = tid & 7, nn0 = tid >> 3;
        #pragma unroll
        for (int j = 0; j < 2; ++j) {
            const int n    = nn0 + j * 32;
            const int ncat = n0 + n;
            const size_t outRow = (size_t)(ncat >> 5) * 128 + g * 32 + (ncat & 31);
            bf16x8 o;
            #pragma unroll
            for (int kk = 0; kk < 8; ++kk) o[kk] = (__bf16)t[kc * 8 + kk][n];
            *(bf16x8*)(Wt + outRow * KDIM + k0 + kc * 8) = o;
        }
    }
}

// ---------------- 256x256 GEMM, tri-buffered BK=32, 1 barrier/step ----------
// LDS (96KB): buf s at s*32768 = { A [256][32]bf16 16KB | B at +16384 }.
// Panel byte addr: row*64 + (chunk ^ ((row>>1)&3))*16  (0-conflict, r3-proven).
__global__ __launch_bounds__(512, 2)
void lstm_gemm_kernel(const __bf16* __restrict__ A, const __bf16* __restrict__ Wt,
                      const float* __restrict__ b_i, const float* __restrict__ b_f,
                      const float* __restrict__ b_o, const float* __restrict__ b_g,
                      const float* __restrict__ c_prev, float* __restrict__ out) {
    extern __shared__ char smem[];   // 98304 B

    const int tid  = threadIdx.x;
    const int wave = tid >> 6;
    const int lane = tid & 63;
    const int wm   = wave >> 2;      // 0..1  (m half: 128 rows each)
    const int wn   = wave & 3;       // 0..3  (64 cat cols each)
    const int l15  = lane & 15;
    const int quad = lane >> 4;

    // XCD swizzle: 512 blocks, 8 XCDs -> 2 cat-panels x 32 by per XCD
    const int bid = blockIdx.x;
    const int bxc = (bid & 7) * 2 + (bid >> 8);   // cat-tile [0,16)
    const int by  = (bid >> 3) & 31;              // m-tile   [0,32)
    const int m0   = by * 256;
    const int cat0 = bxc * 256;
    const int n0   = bxc * 64;

    // ---- staging: panel [256][32]bf16 = 16KB = 2 loads/thread (8KB each).
    // thread -> byte tid*16 (+8192 for rows 128..255): row tid>>2, chunk tid&3;
    // inverse-swizzled global chunk = (tid&3) ^ ((tid>>3)&3).
    const int srow = tid >> 2;
    const int sgch = (tid & 3) ^ ((tid >> 3) & 3);
    const __bf16* Ags = A  + (size_t)(m0   + srow) * KDIM + sgch * 8;
    const __bf16* Bgs = Wt + (size_t)(cat0 + srow) * KDIM + sgch * 8;
    char* ldsw = smem + wave * 1024;   // + lane*16 implicit in global_load_lds

#define STG(o, kt, s) do { \
    const __bf16* gp_ = ((o) ? Bgs : Ags) + (size_t)(kt) * 32; \
    char* lp_ = ldsw + (s) * 32768 + (o) * 16384; \
    async_cp16(gp_, lp_); \
    async_cp16(gp_ + (size_t)128 * KDIM, lp_ + 8192); \
} while (0)

    // ---- fragment read offsets: row r, k-chunk quad -> r*64 + (quad^((r>>1)&3))*16
    const int swz   = (quad ^ ((l15 >> 1) & 3)) * 16;
    const int abase = (wm * 128 + l15) * 64 + swz;                              // + mi*1024
    const int bbase = 16384 + ((wn >> 1) * 128 + (wn & 1) * 64 + l15) * 64 + swz; // + nt*1024

    f32x4 acc[8][4];
    #pragma unroll
    for (int i = 0; i < 8; ++i)
        #pragma unroll
        for (int j = 0; j < 4; ++j) acc[i][j] = (f32x4){0.f, 0.f, 0.f, 0.f};

    // ---- prologue: stage step0 -> buf0, step1 -> buf1; publish step0
    STG(0, 0, 0); STG(1, 0, 0);
    STG(0, 1, 1); STG(1, 1, 1);
    asm volatile("s_waitcnt vmcnt(4)" ::: "memory");   // step0 landed
    BARM;

    int cur = 0;
    for (int t = 0; t < NK; ++t) {
        // stage step t+2 into buf (cur+2)%3 (free: nobody reads it this step)
        int stg = cur - 1; if (stg < 0) stg = 2;       // == (cur+2)%3
        if (t + 2 < NK) { STG(0, t + 2, stg); STG(1, t + 2, stg); }

        const char* bp = smem + cur * 32768;
        bf16x8 af[8], bfr[4];
        #pragma unroll
        for (int mi = 0; mi < 8; ++mi) af[mi]  = *(const bf16x8*)(bp + abase + mi * 1024);
        #pragma unroll
        for (int nt = 0; nt < 4; ++nt) bfr[nt] = *(const bf16x8*)(bp + bbase + nt * 1024);

        __builtin_amdgcn_s_setprio(1);
        #pragma unroll
        for (int mi = 0; mi < 8; ++mi)
            #pragma unroll
            for (int nt = 0; nt < 4; ++nt)
                acc[mi][nt] = __builtin_amdgcn_mfma_f32_16x16x32_bf16(af[mi], bfr[nt], acc[mi][nt], 0, 0, 0);
        __builtin_amdgcn_s_setprio(0);

        // step-end: drain step t+1's loads (issued at t-1); keep t+2's 4 in flight
        if (t < NK - 2) { asm volatile("s_waitcnt vmcnt(4)" ::: "memory"); }
        else            { asm volatile("s_waitcnt vmcnt(0)" ::: "memory"); }
        BARM;
        ++cur; if (cur == 3) cur = 0;
    }

    // ---- epilogue: 4 passes of 64 m-rows; Ep[64][258] f32 (66KB, 2-way banks)
    float* Ep = (float*)smem;
    const int nn = tid & 63;
    const float bvi = b_i[n0 + nn], bvf = b_f[n0 + nn];
    const float bvo = b_o[n0 + nn], bvg = b_g[n0 + nn];
    int colW[4];
    #pragma unroll
    for (int nt = 0; nt < 4; ++nt)
        colW[nt] = ((wn & 1) * 2 + (nt >> 1)) * 64 + (wn >> 1) * 32 + (nt & 1) * 16 + l15;

    #pragma unroll
    for (int ch = 0; ch < 4; ++ch) {
        __syncthreads();
        if (wm == (ch >> 1)) {
            #pragma unroll
            for (int mi = 0; mi < 4; ++mi) {
                const int mt = (ch & 1) * 4 + mi;
                #pragma unroll
                for (int nt = 0; nt < 4; ++nt)
                    #pragma unroll
                    for (int r = 0; r < 4; ++r)
                        Ep[(mi * 16 + quad * 4 + r) * 258 + colW[nt]] = acc[mt][nt][r];
            }
        }
        __syncthreads();
        #pragma unroll
        for (int e = 0; e < 8; ++e) {
            const int row = e * 8 + wave;
            const float gi = sigm(Ep[row * 258 + nn] + bvi);
            const float gf = sigm(Ep[row * 258 + 64 + nn] + bvf);
            const float go = sigm(Ep[row * 258 + 128 + nn] + bvo);
            const float gg = tanh_fast(Ep[row * 258 + 192 + nn] + bvg);
            const size_t pos = (size_t)(m0 + ch * 64 + row) * NDIM + n0 + nn;
            const float cp = c_prev[pos];
            const float cv = gf * cp + gi * gg;
            out[pos] = go * tanh_fast(cv);                 // h
            out[(size_t)BDIM * NDIM + pos] = cv;           // c
        }
    }
#undef STG
}

extern "C" void kernel_launch(void* const* d_in, const int* in_sizes, int n_in,
                              void* d_out, int out_size, void* d_ws, size_t ws_size,
                              hipStream_t stream) {
    const float* Z  = (const float*)d_in[0];
    const float* H  = (const float*)d_in[1];
    const float* Cp = (const float*)d_in[2];
    const float* Wi = (const float*)d_in[3];
    const float* bi = (const float*)d_in[4];
    const float* Wf = (const float*)d_in[5];
    const float* bf = (const float*)d_in[6];
    const float* Wo = (const float*)d_in[7];
    const float* bo = (const float*)d_in[8];
    const float* Wg = (const float*)d_in[9];
    const float* bg = (const float*)d_in[10];

    __bf16* Acomb = (__bf16*)d_ws;                              // 32 MB
    __bf16* Wt    = (__bf16*)((char*)d_ws + (size_t)33554432);  // 16 MB

    static bool cfg = false;
    if (!cfg) {
        hipFuncSetAttribute(reinterpret_cast<const void*>(lstm_gemm_kernel),
                            hipFuncAttributeMaxDynamicSharedMemorySize, 98304);
        cfg = true;
    }

    prep_kernel<<<10240, 256, 0, stream>>>(Z, H, Wi, Wf, Wo, Wg, Acomb, Wt);
    lstm_gemm_kernel<<<512, 512, 98304, stream>>>(
        Acomb, Wt, bi, bf, bo, bg, Cp, (float*)d_out);
}